// Round 4
// baseline (345.900 us; speedup 1.0000x reference)
//
#include <hip/hip_runtime.h>
#include <cstdint>

typedef unsigned long long u64;
typedef unsigned int u32;

#define NB 4096
#define NW 64            // 64-bit words per mask row
#define MM 20
#define HH 16
#define COND_THRES 0.2f
#define IOU_THRES 0.3f
#define PI_F  3.14159265358979323846f
#define PI4_F 0.78539816339744830962f

// ---- workspace layout (bytes) ----
#define WS_KEYS    0                           // u64[NB] (dead after k_gather)
#define WS_KEPT    WS_KEYS                     // u64[64] kept bitmask (aliases keys)
#define WS_MASK    32768                       // u64[NB*NW] = 2 MiB
#define WS_BOX9S   (WS_MASK + NB*NW*8)         // float[NB*9]
#define WS_BEVS    (WS_BOX9S + NB*9*4)         // float4[NB]
#define WS_SCORES  (WS_BEVS + NB*16)           // float[NB]
#define WS_LABELS  (WS_SCORES + NB*4)          // int[NB]
#define WS_SUPSTEP (WS_LABELS + NB*4)          // int[NB]

// ---------- K1: sort keys. Ascending sort on (~score_bits << 12) | idx
__global__ void k_keys(const float* __restrict__ scores, u64* __restrict__ keys) {
  int i = blockIdx.x * blockDim.x + threadIdx.x;
  if (i >= NB) return;
  float s = scores[i];
  u32 sb = (s > COND_THRES) ? __float_as_uint(s) : 0u;
  keys[i] = ((u64)(sb ^ 0xFFFFFFFFu) << 12) | (u64)i;
}

// ---------- K2: single-block bitonic sort of 4096 u64 keys
__global__ void __launch_bounds__(1024) k_sort(u64* __restrict__ keys) {
  __shared__ u64 k[NB];
  for (int t = threadIdx.x; t < NB; t += 1024) k[t] = keys[t];
  __syncthreads();
  for (int len = 2; len <= NB; len <<= 1) {
    for (int s = len >> 1; s > 0; s >>= 1) {
      for (int idx = threadIdx.x; idx < NB; idx += 1024) {
        int j = idx ^ s;
        if (j > idx) {
          bool up = ((idx & len) == 0);
          u64 a = k[idx], b = k[j];
          if ((a > b) == up) { k[idx] = b; k[j] = a; }
        }
      }
      __syncthreads();
    }
  }
  for (int t = threadIdx.x; t < NB; t += 1024) keys[t] = k[t];
}

// ---------- K3: gather sorted arrays + compute axis-aligned BEV boxes
__global__ void k_gather(const u64* __restrict__ keys, const float* __restrict__ boxes9,
                         const float* __restrict__ scores, const int* __restrict__ labels,
                         float* __restrict__ box9s, float4* __restrict__ bevs,
                         float* __restrict__ scoress, int* __restrict__ labelss) {
  #pragma clang fp contract(off)
  int r = blockIdx.x * blockDim.x + threadIdx.x;
  if (r >= NB) return;
  int idx = (int)(keys[r] & 0xFFFu);
  float b[9];
  #pragma unroll
  for (int f = 0; f < 9; ++f) b[f] = boxes9[idx * 9 + f];
  #pragma unroll
  for (int f = 0; f < 9; ++f) box9s[r * 9 + f] = b[f];
  float ang = b[6] - floorf(b[6] / PI_F + 0.5f) * PI_F;
  bool sw = fabsf(ang) >= PI4_F;
  float dx = sw ? b[4] : b[3];
  float dy = sw ? b[3] : b[4];
  bevs[r] = make_float4(b[0] - dx * 0.5f, b[1] - dy * 0.5f,
                        b[0] + dx * 0.5f, b[1] + dy * 0.5f);
  scoress[r] = scores[idx];
  labelss[r] = labels[idx];
}

// ---------- K4: pairwise over-matrix (symmetric), bit-packed rows.
__global__ void __launch_bounds__(64) k_mask(const float4* __restrict__ bevs,
                                             const int* __restrict__ labelss,
                                             u64* __restrict__ mask) {
  #pragma clang fp contract(off)
  __shared__ float4 bj[64];
  __shared__ int lj[64];
  int t = threadIdx.x;
  int jt = blockIdx.x;
  int it = blockIdx.y;
  bj[t] = bevs[jt * 64 + t];
  lj[t] = labelss[jt * 64 + t];
  int i = it * 64 + t;
  float4 a = bevs[i];
  int la = labelss[i];
  float area_a = (a.z - a.x) * (a.w - a.y);
  __syncthreads();
  u64 w = 0;
  #pragma unroll 8
  for (int kk = 0; kk < 64; ++kk) {
    float4 bb = bj[kk];
    float xmin = fmaxf(a.x, bb.x), ymin = fmaxf(a.y, bb.y);
    float xmax = fminf(a.z, bb.z), ymax = fminf(a.w, bb.w);
    float inter = fmaxf(xmax - xmin, 0.0f) * fmaxf(ymax - ymin, 0.0f);
    float area_b = (bb.z - bb.x) * (bb.w - bb.y);
    float iou = inter / fmaxf(area_a + area_b - inter, 1e-6f);
    if ((iou > IOU_THRES) && (la == lj[kk])) w |= (1ull << kk);
  }
  mask[(u64)i * NW + jt] = w;
}

// ---------- K5: kept-mask. Wave 0 consumes rows from LDS (scalar-shadow
// greedy closure); waves 1-3 stage 128-row super-chunks global->LDS,
// double-buffered (2 x 64 KiB). 32 barriers total.
#define SC 128                   // rows per super-chunk
#define NCH (NB / SC)            // 32
__device__ __forceinline__ u64 bcast64(u64 v, int l) {
  u32 lo = __builtin_amdgcn_readlane((u32)v, l);
  u32 hi = __builtin_amdgcn_readlane((u32)(v >> 32), l);
  return ((u64)hi << 32) | (u64)lo;
}
__global__ void __launch_bounds__(256) k_keep(const u64* __restrict__ mask,
                                              const float* __restrict__ scoress,
                                              u64* __restrict__ keptOut) {
  __shared__ __align__(16) u64 buf[2][SC * 64];   // 128 KiB
  int tid = threadIdx.x;
  int lane = tid & 63;
  int wave = tid >> 6;
  u64 sup = 0, kept = 0;
  if (wave == 0) {
    // init sup with invalid bits: ballot at iter t gives exactly word t
    for (int t = 0; t < 64; ++t) {
      u64 bb = __ballot(!(scoress[(t << 6) | lane] > COND_THRES));
      if (lane == t) sup = bb;
    }
  } else {
    // preload chunk 0
    const ulonglong2* src2 = (const ulonglong2*)mask;
    ulonglong2* dst2 = (ulonglong2*)buf[0];
    for (int rp = wave - 1; rp < SC / 2; rp += 3)
      dst2[rp * 64 + lane] = src2[rp * 64 + lane];
  }
  __syncthreads();
  for (int c = 0; c < NCH; ++c) {
    if (wave != 0) {
      if (c + 1 < NCH) {
        const ulonglong2* src2 = (const ulonglong2*)(mask + (u64)(c + 1) * SC * 64);
        ulonglong2* dst2 = (ulonglong2*)buf[(c + 1) & 1];
        for (int rp = wave - 1; rp < SC / 2; rp += 3)
          dst2[rp * 64 + lane] = src2[rp * 64 + lane];
      }
    } else {
      const u64* lbuf = buf[c & 1];
      #pragma unroll
      for (int g = 0; g < SC / 64; ++g) {        // 2 groups of 64 boxes
        const int cw = c * (SC / 64) + g;
        u64 scur = bcast64(sup, cw);
        u64 cur[8];
        #pragma unroll
        for (int k = 0; k < 8; ++k) cur[k] = lbuf[(g * 64 + k) * 64 + lane];
        #pragma unroll
        for (int q = 0; q < 8; ++q) {
          u64 nxt[8];
          if (q < 7) {
            #pragma unroll
            for (int k = 0; k < 8; ++k)
              nxt[k] = lbuf[(g * 64 + (q + 1) * 8 + k) * 64 + lane];
          }
          #pragma unroll
          for (int k = 0; k < 8; ++k) {
            const int ib = q * 8 + k;
            if (!((scur >> ib) & 1ull)) {        // box kept (uniform branch)
              u64 row = cur[k];
              sup |= row;
              scur |= bcast64(row, cw);
              if (lane == cw) kept |= (1ull << ib);
            }
          }
          if (q < 7) {
            #pragma unroll
            for (int k = 0; k < 8; ++k) cur[k] = nxt[k];
          }
        }
      }
    }
    __syncthreads();
  }
  if (wave == 0) keptOut[lane] = kept;
}

// ---------- K5b: supstep[j] = min{i kept : over(i,j)} (parallel), -1 if invalid.
__global__ void __launch_bounds__(256) k_supstep(const u64* __restrict__ mask,
                                                 const u64* __restrict__ kept,
                                                 const float* __restrict__ scoress,
                                                 int* __restrict__ supstep) {
  __shared__ u64 K[64];
  if (threadIdx.x < 64) K[threadIdx.x] = kept[threadIdx.x];
  __syncthreads();
  int j = blockIdx.x * 256 + threadIdx.x;
  if (!(scoress[j] > COND_THRES)) { supstep[j] = -1; return; }
  int res = 0x7FFFFFFF;
  #pragma unroll 4
  for (int w = 0; w < 64; ++w) {
    u64 m = mask[(u64)j * NW + w] & K[w];
    if (m) { res = (w << 6) + __builtin_ctzll(m); break; }
  }
  supstep[j] = res;
}

// ---------- K6: per-box merge + all outputs. One 64-thread block per sorted box.
__global__ void __launch_bounds__(64) k_merge(
    const u64* __restrict__ mask, const int* __restrict__ supstep,
    const float* __restrict__ box9s, const float* __restrict__ scoress,
    const int* __restrict__ labelss,
    const float* __restrict__ w1, const float* __restrict__ b1,
    const float* __restrict__ w2, const float* __restrict__ b2,
    const float* __restrict__ w3, const float* __restrict__ b3,
    float* __restrict__ out) {
  #pragma clang fp contract(off)
  __shared__ int candList[MM];
  __shared__ float ob[MM][7];
  __shared__ float h1[7][HH];
  __shared__ float h2[7][HH];
  __shared__ float res[7];
  int i = blockIdx.x;
  int t = threadIdx.x;
  bool active = (supstep[i] == i);
  u64 wq = 0;
  int cnt = 0;
  if (active) {
    u64 w = mask[(u64)i * NW + t];
    while (w) {
      int b = __builtin_ctzll(w);
      w &= w - 1;
      int j = (t << 6) | b;
      if (supstep[j] >= i) { wq |= (1ull << b); cnt++; }
    }
  }
  int incl = cnt;
  #pragma unroll
  for (int off = 1; off < 64; off <<= 1) {
    int v = __shfl_up(incl, off);
    if (t >= off) incl += v;
  }
  int excl = incl - cnt;
  int count = __shfl(incl, 63);
  bool merged = active && (count > 1);
  if (merged && wq) {
    int pos = excl;
    u64 ww = wq;
    while (ww && pos < MM) {
      int b = __builtin_ctzll(ww);
      ww &= ww - 1;
      candList[pos++] = (t << 6) | b;
    }
  }
  __syncthreads();
  if (merged) {
    int nc = count < MM ? count : MM;
    if (t < MM) {
      if (t < nc) {
        int j = candList[t];
        #pragma unroll
        for (int f = 0; f < 7; ++f) ob[t][f] = box9s[j * 9 + f];
      } else {
        #pragma unroll
        for (int f = 0; f < 7; ++f) ob[t][f] = 0.0f;
      }
    }
    __syncthreads();
    for (int o = t; o < 7 * HH; o += 64) {
      int f = o >> 4, hh = o & 15;
      float acc = b1[hh];
      #pragma unroll
      for (int m = 0; m < MM; ++m) acc += ob[m][f] * w1[m * HH + hh];
      h1[f][hh] = fmaxf(acc, 0.0f);
    }
    __syncthreads();
    for (int o = t; o < 7 * HH; o += 64) {
      int f = o >> 4, oo = o & 15;
      float acc = b2[oo];
      #pragma unroll
      for (int k = 0; k < HH; ++k) acc += h1[f][k] * w2[k * HH + oo];
      h2[f][oo] = fmaxf(acc, 0.0f);
    }
    __syncthreads();
    if (t < 7) {
      float acc = b3[0];
      #pragma unroll
      for (int k = 0; k < HH; ++k) acc += h2[t][k] * w3[k];
      if (t >= 3 && t < 6) acc = fmaxf(acc, 1e-5f);
      res[t] = acc;
    }
    __syncthreads();
  }
  if (t < 9) {
    float v = box9s[i * 9 + t];
    if (merged && t < 7) v = res[t];
    out[i * 9 + t] = v;
  }
  if (t == 0) {
    out[NB * 9 + i]          = scoress[i];
    out[NB * 9 + NB + i]     = (float)labelss[i];
    out[NB * 9 + 2 * NB + i] = active ? 1.0f : 0.0f;
  }
}

extern "C" void kernel_launch(void* const* d_in, const int* in_sizes, int n_in,
                              void* d_out, int out_size, void* d_ws, size_t ws_size,
                              hipStream_t stream) {
  const float* boxes9 = (const float*)d_in[0];
  const float* scores = (const float*)d_in[1];
  const int*   labels = (const int*)d_in[2];
  const float* w1 = (const float*)d_in[3];
  const float* b1 = (const float*)d_in[4];
  const float* w2 = (const float*)d_in[5];
  const float* b2 = (const float*)d_in[6];
  const float* w3 = (const float*)d_in[7];
  const float* b3 = (const float*)d_in[8];
  char* ws = (char*)d_ws;
  u64*    keys    = (u64*)(ws + WS_KEYS);
  u64*    kept    = (u64*)(ws + WS_KEPT);
  u64*    mask    = (u64*)(ws + WS_MASK);
  float*  box9s   = (float*)(ws + WS_BOX9S);
  float4* bevs    = (float4*)(ws + WS_BEVS);
  float*  scoress = (float*)(ws + WS_SCORES);
  int*    labelss = (int*)(ws + WS_LABELS);
  int*    supstep = (int*)(ws + WS_SUPSTEP);
  float*  out     = (float*)d_out;

  hipLaunchKernelGGL(k_keys,    dim3(NB / 256), dim3(256),  0, stream, scores, keys);
  hipLaunchKernelGGL(k_sort,    dim3(1),        dim3(1024), 0, stream, keys);
  hipLaunchKernelGGL(k_gather,  dim3(NB / 256), dim3(256),  0, stream, keys, boxes9, scores, labels,
                     box9s, bevs, scoress, labelss);
  hipLaunchKernelGGL(k_mask,    dim3(64, 64),   dim3(64),   0, stream, bevs, labelss, mask);
  hipLaunchKernelGGL(k_keep,    dim3(1),        dim3(256),  0, stream, mask, scoress, kept);
  hipLaunchKernelGGL(k_supstep, dim3(NB / 256), dim3(256),  0, stream, mask, kept, scoress, supstep);
  hipLaunchKernelGGL(k_merge,   dim3(NB),       dim3(64),   0, stream, mask, supstep,
                     box9s, scoress, labelss, w1, b1, w2, b2, w3, b3, out);
}

// Round 5
// 283.903 us; speedup vs baseline: 1.2184x; 1.2184x over previous
//
#include <hip/hip_runtime.h>
#include <cstdint>

typedef unsigned long long u64;
typedef unsigned int u32;

#define NB 4096
#define NW 64            // 64-bit words per mask row
#define MM 20
#define HH 16
#define COND_THRES 0.2f
#define IOU_THRES 0.3f
#define PI_F  3.14159265358979323846f
#define PI4_F 0.78539816339744830962f

// ---- workspace layout (bytes) ----
#define WS_KEYS    0                           // u64[NB] (dead after k_gather)
#define WS_KEPT    WS_KEYS                     // u64[64] kept bitmask (aliases keys)
#define WS_MASK    32768                       // u64[NB*NW] = 2 MiB
#define WS_BOX9S   (WS_MASK + NB*NW*8)         // float[NB*9]
#define WS_BEVS    (WS_BOX9S + NB*9*4)         // float4[NB]
#define WS_SCORES  (WS_BEVS + NB*16)           // float[NB]
#define WS_LABELS  (WS_SCORES + NB*4)          // int[NB]
#define WS_SUPSTEP (WS_LABELS + NB*4)          // int[NB]

// ---------- K1: sort keys. Ascending sort on (~score_bits << 12) | idx
__global__ void k_keys(const float* __restrict__ scores, u64* __restrict__ keys) {
  int i = blockIdx.x * blockDim.x + threadIdx.x;
  if (i >= NB) return;
  float s = scores[i];
  u32 sb = (s > COND_THRES) ? __float_as_uint(s) : 0u;
  keys[i] = ((u64)(sb ^ 0xFFFFFFFFu) << 12) | (u64)i;
}

// ---------- K2: single-block bitonic sort of 4096 u64 keys
__global__ void __launch_bounds__(1024) k_sort(u64* __restrict__ keys) {
  __shared__ u64 k[NB];
  for (int t = threadIdx.x; t < NB; t += 1024) k[t] = keys[t];
  __syncthreads();
  for (int len = 2; len <= NB; len <<= 1) {
    for (int s = len >> 1; s > 0; s >>= 1) {
      for (int idx = threadIdx.x; idx < NB; idx += 1024) {
        int j = idx ^ s;
        if (j > idx) {
          bool up = ((idx & len) == 0);
          u64 a = k[idx], b = k[j];
          if ((a > b) == up) { k[idx] = b; k[j] = a; }
        }
      }
      __syncthreads();
    }
  }
  for (int t = threadIdx.x; t < NB; t += 1024) keys[t] = k[t];
}

// ---------- K3: gather sorted arrays + compute axis-aligned BEV boxes
__global__ void k_gather(const u64* __restrict__ keys, const float* __restrict__ boxes9,
                         const float* __restrict__ scores, const int* __restrict__ labels,
                         float* __restrict__ box9s, float4* __restrict__ bevs,
                         float* __restrict__ scoress, int* __restrict__ labelss) {
  #pragma clang fp contract(off)
  int r = blockIdx.x * blockDim.x + threadIdx.x;
  if (r >= NB) return;
  int idx = (int)(keys[r] & 0xFFFu);
  float b[9];
  #pragma unroll
  for (int f = 0; f < 9; ++f) b[f] = boxes9[idx * 9 + f];
  #pragma unroll
  for (int f = 0; f < 9; ++f) box9s[r * 9 + f] = b[f];
  float ang = b[6] - floorf(b[6] / PI_F + 0.5f) * PI_F;
  bool sw = fabsf(ang) >= PI4_F;
  float dx = sw ? b[4] : b[3];
  float dy = sw ? b[3] : b[4];
  bevs[r] = make_float4(b[0] - dx * 0.5f, b[1] - dy * 0.5f,
                        b[0] + dx * 0.5f, b[1] + dy * 0.5f);
  scoress[r] = scores[idx];
  labelss[r] = labels[idx];
}

// ---------- K4: pairwise over-matrix (symmetric), bit-packed rows.
__global__ void __launch_bounds__(64) k_mask(const float4* __restrict__ bevs,
                                             const int* __restrict__ labelss,
                                             u64* __restrict__ mask) {
  #pragma clang fp contract(off)
  __shared__ float4 bj[64];
  __shared__ int lj[64];
  int t = threadIdx.x;
  int jt = blockIdx.x;
  int it = blockIdx.y;
  bj[t] = bevs[jt * 64 + t];
  lj[t] = labelss[jt * 64 + t];
  int i = it * 64 + t;
  float4 a = bevs[i];
  int la = labelss[i];
  float area_a = (a.z - a.x) * (a.w - a.y);
  __syncthreads();
  u64 w = 0;
  #pragma unroll 8
  for (int kk = 0; kk < 64; ++kk) {
    float4 bb = bj[kk];
    float xmin = fmaxf(a.x, bb.x), ymin = fmaxf(a.y, bb.y);
    float xmax = fminf(a.z, bb.z), ymax = fminf(a.w, bb.w);
    float inter = fmaxf(xmax - xmin, 0.0f) * fmaxf(ymax - ymin, 0.0f);
    float area_b = (bb.z - bb.x) * (bb.w - bb.y);
    float iou = inter / fmaxf(area_a + area_b - inter, 1e-6f);
    if ((iou > IOU_THRES) && (la == lj[kk])) w |= (1ull << kk);
  }
  mask[(u64)i * NW + jt] = w;
}

// ---------- K5: kept-mask. Wave 0 consumes rows from LDS (scalar-shadow
// greedy closure); waves 1-15 stage 128-row super-chunks global->LDS,
// double-buffered (2 x 64 KiB). Producer loads batched 5-deep in registers
// (back-to-back issue -> ~75 KiB in flight across 15 waves).
#define SC 128                   // rows per super-chunk
#define NCH (NB / SC)            // 32
#define PW 15                    // producer waves
__device__ __forceinline__ u64 bcast64(u64 v, int l) {
  u32 lo = __builtin_amdgcn_readlane((u32)v, l);
  u32 hi = __builtin_amdgcn_readlane((u32)(v >> 32), l);
  return ((u64)hi << 32) | (u64)lo;
}
__device__ __forceinline__ void stage_chunk(const u64* __restrict__ mask, u64* __restrict__ dst,
                                            int chunk, int wave, int lane) {
  const ulonglong2* __restrict__ src2 = (const ulonglong2*)(mask + (u64)chunk * SC * 64);
  ulonglong2* dst2 = (ulonglong2*)dst;
  ulonglong2 tmp[5];
  #pragma unroll
  for (int p = 0; p < 5; ++p) {
    int ci = (wave - 1) + PW * p;
    if (ci < 64) tmp[p] = src2[ci * 64 + lane];   // back-to-back issue, no deps
  }
  #pragma unroll
  for (int p = 0; p < 5; ++p) {
    int ci = (wave - 1) + PW * p;
    if (ci < 64) dst2[ci * 64 + lane] = tmp[p];
  }
}
__global__ void __launch_bounds__(1024) k_keep(const u64* __restrict__ mask,
                                               const float* __restrict__ scoress,
                                               u64* __restrict__ keptOut) {
  __shared__ __align__(16) u64 buf[2][SC * 64];   // 128 KiB
  int tid = threadIdx.x;
  int lane = tid & 63;
  int wave = tid >> 6;
  u64 sup = 0, kept = 0;
  if (wave == 0) {
    // init sup with invalid bits: ballot at iter t gives exactly word t
    for (int t = 0; t < 64; ++t) {
      u64 bb = __ballot(!(scoress[(t << 6) | lane] > COND_THRES));
      if (lane == t) sup = bb;
    }
  } else {
    stage_chunk(mask, buf[0], 0, wave, lane);
  }
  __syncthreads();
  for (int c = 0; c < NCH; ++c) {
    if (wave != 0) {
      if (c + 1 < NCH) stage_chunk(mask, buf[(c + 1) & 1], c + 1, wave, lane);
    } else {
      const u64* lbuf = buf[c & 1];
      #pragma unroll
      for (int g = 0; g < SC / 64; ++g) {        // 2 groups of 64 boxes
        const int cw = c * (SC / 64) + g;
        u64 scur = bcast64(sup, cw);
        u64 cur[8];
        #pragma unroll
        for (int k = 0; k < 8; ++k) cur[k] = lbuf[(g * 64 + k) * 64 + lane];
        #pragma unroll
        for (int q = 0; q < 8; ++q) {
          u64 nxt[8];
          if (q < 7) {
            #pragma unroll
            for (int k = 0; k < 8; ++k)
              nxt[k] = lbuf[(g * 64 + (q + 1) * 8 + k) * 64 + lane];
          }
          #pragma unroll
          for (int k = 0; k < 8; ++k) {
            const int ib = q * 8 + k;
            if (!((scur >> ib) & 1ull)) {        // box kept (uniform branch)
              u64 row = cur[k];
              sup |= row;
              scur |= bcast64(row, cw);
              if (lane == cw) kept |= (1ull << ib);
            }
          }
          if (q < 7) {
            #pragma unroll
            for (int k = 0; k < 8; ++k) cur[k] = nxt[k];
          }
        }
      }
    }
    __syncthreads();
  }
  if (wave == 0) keptOut[lane] = kept;
}

// ---------- K5b: supstep[j] = min{i kept : over(i,j)} (parallel), -1 if invalid.
__global__ void __launch_bounds__(256) k_supstep(const u64* __restrict__ mask,
                                                 const u64* __restrict__ kept,
                                                 const float* __restrict__ scoress,
                                                 int* __restrict__ supstep) {
  __shared__ u64 K[64];
  if (threadIdx.x < 64) K[threadIdx.x] = kept[threadIdx.x];
  __syncthreads();
  int j = blockIdx.x * 256 + threadIdx.x;
  if (!(scoress[j] > COND_THRES)) { supstep[j] = -1; return; }
  int res = 0x7FFFFFFF;
  #pragma unroll 4
  for (int w = 0; w < 64; ++w) {
    u64 m = mask[(u64)j * NW + w] & K[w];
    if (m) { res = (w << 6) + __builtin_ctzll(m); break; }
  }
  supstep[j] = res;
}

// ---------- K6: per-box merge + all outputs. One 64-thread block per sorted box.
__global__ void __launch_bounds__(64) k_merge(
    const u64* __restrict__ mask, const int* __restrict__ supstep,
    const float* __restrict__ box9s, const float* __restrict__ scoress,
    const int* __restrict__ labelss,
    const float* __restrict__ w1, const float* __restrict__ b1,
    const float* __restrict__ w2, const float* __restrict__ b2,
    const float* __restrict__ w3, const float* __restrict__ b3,
    float* __restrict__ out) {
  #pragma clang fp contract(off)
  __shared__ int candList[MM];
  __shared__ float ob[MM][7];
  __shared__ float h1[7][HH];
  __shared__ float h2[7][HH];
  __shared__ float res[7];
  int i = blockIdx.x;
  int t = threadIdx.x;
  bool active = (supstep[i] == i);
  u64 wq = 0;
  int cnt = 0;
  if (active) {
    u64 w = mask[(u64)i * NW + t];
    while (w) {
      int b = __builtin_ctzll(w);
      w &= w - 1;
      int j = (t << 6) | b;
      if (supstep[j] >= i) { wq |= (1ull << b); cnt++; }
    }
  }
  int incl = cnt;
  #pragma unroll
  for (int off = 1; off < 64; off <<= 1) {
    int v = __shfl_up(incl, off);
    if (t >= off) incl += v;
  }
  int excl = incl - cnt;
  int count = __shfl(incl, 63);
  bool merged = active && (count > 1);
  if (merged && wq) {
    int pos = excl;
    u64 ww = wq;
    while (ww && pos < MM) {
      int b = __builtin_ctzll(ww);
      ww &= ww - 1;
      candList[pos++] = (t << 6) | b;
    }
  }
  __syncthreads();
  if (merged) {
    int nc = count < MM ? count : MM;
    if (t < MM) {
      if (t < nc) {
        int j = candList[t];
        #pragma unroll
        for (int f = 0; f < 7; ++f) ob[t][f] = box9s[j * 9 + f];
      } else {
        #pragma unroll
        for (int f = 0; f < 7; ++f) ob[t][f] = 0.0f;
      }
    }
    __syncthreads();
    for (int o = t; o < 7 * HH; o += 64) {
      int f = o >> 4, hh = o & 15;
      float acc = b1[hh];
      #pragma unroll
      for (int m = 0; m < MM; ++m) acc += ob[m][f] * w1[m * HH + hh];
      h1[f][hh] = fmaxf(acc, 0.0f);
    }
    __syncthreads();
    for (int o = t; o < 7 * HH; o += 64) {
      int f = o >> 4, oo = o & 15;
      float acc = b2[oo];
      #pragma unroll
      for (int k = 0; k < HH; ++k) acc += h1[f][k] * w2[k * HH + oo];
      h2[f][oo] = fmaxf(acc, 0.0f);
    }
    __syncthreads();
    if (t < 7) {
      float acc = b3[0];
      #pragma unroll
      for (int k = 0; k < HH; ++k) acc += h2[t][k] * w3[k];
      if (t >= 3 && t < 6) acc = fmaxf(acc, 1e-5f);
      res[t] = acc;
    }
    __syncthreads();
  }
  if (t < 9) {
    float v = box9s[i * 9 + t];
    if (merged && t < 7) v = res[t];
    out[i * 9 + t] = v;
  }
  if (t == 0) {
    out[NB * 9 + i]          = scoress[i];
    out[NB * 9 + NB + i]     = (float)labelss[i];
    out[NB * 9 + 2 * NB + i] = active ? 1.0f : 0.0f;
  }
}

extern "C" void kernel_launch(void* const* d_in, const int* in_sizes, int n_in,
                              void* d_out, int out_size, void* d_ws, size_t ws_size,
                              hipStream_t stream) {
  const float* boxes9 = (const float*)d_in[0];
  const float* scores = (const float*)d_in[1];
  const int*   labels = (const int*)d_in[2];
  const float* w1 = (const float*)d_in[3];
  const float* b1 = (const float*)d_in[4];
  const float* w2 = (const float*)d_in[5];
  const float* b2 = (const float*)d_in[6];
  const float* w3 = (const float*)d_in[7];
  const float* b3 = (const float*)d_in[8];
  char* ws = (char*)d_ws;
  u64*    keys    = (u64*)(ws + WS_KEYS);
  u64*    kept    = (u64*)(ws + WS_KEPT);
  u64*    mask    = (u64*)(ws + WS_MASK);
  float*  box9s   = (float*)(ws + WS_BOX9S);
  float4* bevs    = (float4*)(ws + WS_BEVS);
  float*  scoress = (float*)(ws + WS_SCORES);
  int*    labelss = (int*)(ws + WS_LABELS);
  int*    supstep = (int*)(ws + WS_SUPSTEP);
  float*  out     = (float*)d_out;

  hipLaunchKernelGGL(k_keys,    dim3(NB / 256), dim3(256),  0, stream, scores, keys);
  hipLaunchKernelGGL(k_sort,    dim3(1),        dim3(1024), 0, stream, keys);
  hipLaunchKernelGGL(k_gather,  dim3(NB / 256), dim3(256),  0, stream, keys, boxes9, scores, labels,
                     box9s, bevs, scoress, labelss);
  hipLaunchKernelGGL(k_mask,    dim3(64, 64),   dim3(64),   0, stream, bevs, labelss, mask);
  hipLaunchKernelGGL(k_keep,    dim3(1),        dim3(1024), 0, stream, mask, scoress, kept);
  hipLaunchKernelGGL(k_supstep, dim3(NB / 256), dim3(256),  0, stream, mask, kept, scoress, supstep);
  hipLaunchKernelGGL(k_merge,   dim3(NB),       dim3(64),   0, stream, mask, supstep,
                     box9s, scoress, labelss, w1, b1, w2, b2, w3, b3, out);
}